// Round 11
// baseline (118.036 us; speedup 1.0000x reference)
//
#include <hip/hip_runtime.h>
#include <math.h>
#include <stdint.h>

// out_i = clamp(out_{i-1}; a_i, a_i+1), a_i = x_i * k.  Clamp functions
// p -> min(max(p,lo),hi) compose associatively -> parallel scan.
//
// R11: SINGLE dispatch. grid=256 blocks = #CUs -> all blocks co-resident by
// capacity (1 block/CU min) -> deterministic software grid barrier (one
// arrive-counter, device-scope release/acquire, s_sleep backoff) is safe
// without cooperative launch. Unlike R3/R6 there is ONE barrier with ~equal
// arrival times, not a data/schedule-dependent poll chain.
// Phase1: block aggregates (R8-proven machinery). Barrier. Phase2: ordered
// reduce over 256 aggs. Phase3: re-read x (L3-hot), apply, NT stores.

#define TPB 256
#define WAVES 4
#define SEGS 4
#define FPL 8
#define SEG_ELEMS (TPB * FPL)            // 2048
#define CHUNK_ELEMS (SEGS * SEG_ELEMS)   // 8192
#define CHUNKS 4
#define BLK_ELEMS (CHUNKS * CHUNK_ELEMS) // 32768 -> 256 blocks @ T=2^23

typedef float v4f __attribute__((ext_vector_type(4)));

__device__ __forceinline__ float clampf(float x, float lo, float hi) {
    return fminf(fmaxf(x, lo), hi);
}
__device__ __forceinline__ uint64_t pack2(float lo, float hi) {
    union { float f[2]; uint64_t u; } u; u.f[0] = lo; u.f[1] = hi; return u.u;
}
__device__ __forceinline__ void unpack2(uint64_t w, float* lo, float* hi) {
    union { uint64_t u; float f[2]; } u; u.u = w; *lo = u.f[0]; *hi = u.f[1];
}

__global__ __launch_bounds__(TPB) void phi_scan(
    const v4f* __restrict__ x4,
    const float* __restrict__ kern,
    const float* __restrict__ state,
    float* __restrict__ out,           // T outputs + 1 new_state
    uint64_t* __restrict__ agg,        // [nblocks] packed (lo,hi)
    uint32_t* __restrict__ counter,
    int nblocks)
{
    __shared__ float wl[SEGS][WAVES], wh[SEGS][WAVES];
    __shared__ float rl[WAVES], rh[WAVES];
    __shared__ float s_v;

    const int t = threadIdx.x, lane = t & 63, w = t >> 6;
    const int b = blockIdx.x;
    const float k = kern[0];
    const size_t blk4 = (size_t)b * (BLK_ELEMS / 4);

    // ---------------- phase 1: block aggregate over 4 ordered chunks --------
    float bLo = -INFINITY, bHi = INFINITY;      // meaningful in t0 only
    for (int c = 0; c < CHUNKS; ++c) {
        const size_t c4 = blk4 + (size_t)c * (CHUNK_ELEMS / 4);
        v4f v[SEGS][2];
#pragma unroll
        for (int s = 0; s < SEGS; ++s) {
            const size_t i4 = c4 + (size_t)s * (SEG_ELEMS / 4) + (size_t)t * 2;
            v[s][0] = x4[i4];                   // plain loads: keep in L2/L3 for phase 3
            v[s][1] = x4[i4 + 1];
        }
#pragma unroll
        for (int s = 0; s < SEGS; ++s) {
            float lo, hi, a;
            a = v[s][0].x * k; lo = a; hi = a + 1.0f;
            a = v[s][0].y * k; lo = clampf(lo, a, a + 1.0f); hi = clampf(hi, a, a + 1.0f);
            a = v[s][0].z * k; lo = clampf(lo, a, a + 1.0f); hi = clampf(hi, a, a + 1.0f);
            a = v[s][0].w * k; lo = clampf(lo, a, a + 1.0f); hi = clampf(hi, a, a + 1.0f);
            a = v[s][1].x * k; lo = clampf(lo, a, a + 1.0f); hi = clampf(hi, a, a + 1.0f);
            a = v[s][1].y * k; lo = clampf(lo, a, a + 1.0f); hi = clampf(hi, a, a + 1.0f);
            a = v[s][1].z * k; lo = clampf(lo, a, a + 1.0f); hi = clampf(hi, a, a + 1.0f);
            a = v[s][1].w * k; lo = clampf(lo, a, a + 1.0f); hi = clampf(hi, a, a + 1.0f);
            // ordered wave reduce: self (earlier) FIRST, lane+off SECOND.
            // OOB shfl returns self; clamp-pair self-compose is identity.
#pragma unroll
            for (int off = 1; off < 64; off <<= 1) {
                float plo = __shfl_down(lo, off);
                float phi_ = __shfl_down(hi, off);
                float nlo = clampf(lo, plo, phi_);
                float nhi = clampf(hi, plo, phi_);
                lo = nlo; hi = nhi;
            }
            if (lane == 0) { wl[s][w] = lo; wh[s][w] = hi; }
        }
        __syncthreads();
        if (t == 0) {
#pragma unroll
            for (int s = 0; s < SEGS; ++s)      // (s,w) lexicographic = element order
#pragma unroll
                for (int i = 0; i < WAVES; ++i) {
                    bLo = clampf(bLo, wl[s][i], wh[s][i]);
                    bHi = clampf(bHi, wl[s][i], wh[s][i]);
                }
        }
        __syncthreads();                        // wl/wh reusable next chunk
    }

    // ---------------- grid barrier (deterministic, one-shot) ----------------
    if (t == 0) {
        __hip_atomic_store(&agg[b], pack2(bLo, bHi),
                           __ATOMIC_RELEASE, __HIP_MEMORY_SCOPE_AGENT);
        __hip_atomic_fetch_add(counter, 1u,
                               __ATOMIC_RELEASE, __HIP_MEMORY_SCOPE_AGENT);
    }
    __syncthreads();
    if (t == 0) {
        while (__hip_atomic_load(counter, __ATOMIC_ACQUIRE,
                                 __HIP_MEMORY_SCOPE_AGENT) < (uint32_t)nblocks)
            __builtin_amdgcn_s_sleep(16);
    }
    __syncthreads();

    // ---------------- phase 2: block entry value from agg[0..b-1] -----------
    {
        float lo = -INFINITY, hi = INFINITY;
        if (t < b) {                            // nblocks == TPB: one agg per thread
            float l, h;
            unpack2(__hip_atomic_load(&agg[t], __ATOMIC_RELAXED,
                                      __HIP_MEMORY_SCOPE_AGENT), &l, &h);
            lo = l; hi = h;
        }
#pragma unroll
        for (int off = 1; off < 64; off <<= 1) {
            float plo = __shfl_down(lo, off);
            float phi_ = __shfl_down(hi, off);
            float nlo = clampf(lo, plo, phi_);
            float nhi = clampf(hi, plo, phi_);
            lo = nlo; hi = nhi;
        }
        if (lane == 0) { rl[w] = lo; rh[w] = hi; }
        __syncthreads();
        if (t == 0) {
            float L = rl[0], H = rh[0];
#pragma unroll
            for (int i = 1; i < WAVES; ++i) {
                L = clampf(L, rl[i], rh[i]);
                H = clampf(H, rl[i], rh[i]);
            }
            s_v = clampf(state[0], L, H);       // block entry VALUE
        }
        __syncthreads();
    }

    // ---------------- phase 3: apply + write (x re-read is L3-hot) ----------
    float p = s_v;
    for (int c = 0; c < CHUNKS; ++c) {
        const size_t c4 = blk4 + (size_t)c * (CHUNK_ELEMS / 4);
        float a[SEGS][FPL];
        float eslo[SEGS], eshi[SEGS], Slo[SEGS], Shi[SEGS];
#pragma unroll
        for (int s = 0; s < SEGS; ++s) {
            const size_t i4 = c4 + (size_t)s * (SEG_ELEMS / 4) + (size_t)t * 2;
            v4f v0 = __builtin_nontemporal_load(&x4[i4]);      // last use of x
            v4f v1 = __builtin_nontemporal_load(&x4[i4 + 1]);
            a[s][0] = v0.x * k; a[s][1] = v0.y * k; a[s][2] = v0.z * k; a[s][3] = v0.w * k;
            a[s][4] = v1.x * k; a[s][5] = v1.y * k; a[s][6] = v1.z * k; a[s][7] = v1.w * k;
            float lo = a[s][0], hi = a[s][0] + 1.0f;
#pragma unroll
            for (int j = 1; j < FPL; ++j) {
                lo = clampf(lo, a[s][j], a[s][j] + 1.0f);
                hi = clampf(hi, a[s][j], a[s][j] + 1.0f);
            }
            // wave inclusive scan on lane pairs (prefix FIRST, self SECOND)
#pragma unroll
            for (int off = 1; off < 64; off <<= 1) {
                float plo = __shfl_up(lo, off);
                float phi_ = __shfl_up(hi, off);
                if (lane >= off) {
                    float nlo = clampf(plo, lo, hi);
                    float nhi = clampf(phi_, lo, hi);
                    lo = nlo; hi = nhi;
                }
            }
            float elo = __shfl_up(lo, 1), ehi = __shfl_up(hi, 1);
            if (lane == 0) { elo = -INFINITY; ehi = INFINITY; }
            eslo[s] = elo; eshi[s] = ehi;
            if (lane == 63) { wl[s][w] = lo; wh[s][w] = hi; }
        }
        __syncthreads();
#pragma unroll
        for (int s = 0; s < SEGS; ++s) {
            float welo = -INFINITY, wehi = INFINITY;   // earlier waves in segment
            for (int i = 0; i < w; ++i) {
                welo = clampf(welo, wl[s][i], wh[s][i]);
                wehi = clampf(wehi, wl[s][i], wh[s][i]);
            }
            float llo = eslo[s], lhi = eshi[s];
            eslo[s] = clampf(welo, llo, lhi);          // compose(waves-bef, lanes-bef)
            eshi[s] = clampf(wehi, llo, lhi);
            float stl = -INFINITY, sth = INFINITY;     // segment total
#pragma unroll
            for (int i = 0; i < WAVES; ++i) {
                stl = clampf(stl, wl[s][i], wh[s][i]);
                sth = clampf(sth, wl[s][i], wh[s][i]);
            }
            Slo[s] = stl; Shi[s] = sth;
        }
#pragma unroll
        for (int s = 0; s < SEGS; ++s) {
            float wv = clampf(p, eslo[s], eshi[s]);    // thread entry in segment
            v4f r0, r1;
            wv = clampf(wv, a[s][0], a[s][0] + 1.0f); r0.x = wv;
            wv = clampf(wv, a[s][1], a[s][1] + 1.0f); r0.y = wv;
            wv = clampf(wv, a[s][2], a[s][2] + 1.0f); r0.z = wv;
            wv = clampf(wv, a[s][3], a[s][3] + 1.0f); r0.w = wv;
            wv = clampf(wv, a[s][4], a[s][4] + 1.0f); r1.x = wv;
            wv = clampf(wv, a[s][5], a[s][5] + 1.0f); r1.y = wv;
            wv = clampf(wv, a[s][6], a[s][6] + 1.0f); r1.z = wv;
            wv = clampf(wv, a[s][7], a[s][7] + 1.0f); r1.w = wv;
            v4f* o = (v4f*)(out + (size_t)b * BLK_ELEMS + (size_t)c * CHUNK_ELEMS
                            + (size_t)s * SEG_ELEMS) + (size_t)t * 2;
            __builtin_nontemporal_store(r0, &o[0]);
            __builtin_nontemporal_store(r1, &o[1]);
            p = clampf(p, Slo[s], Shi[s]);             // advance past segment
        }
        __syncthreads();                                // wl/wh reusable next chunk
    }

    // p (uniform) = value after the block's last element
    if (b == nblocks - 1 && t == 0)
        out[(size_t)nblocks * BLK_ELEMS] = p;           // new_state = last output
}

extern "C" void kernel_launch(void* const* d_in, const int* in_sizes, int n_in,
                              void* d_out, int out_size, void* d_ws, size_t ws_size,
                              hipStream_t stream) {
    const v4f* x4      = (const v4f*)d_in[0];      // [1,T]
    const float* state = (const float*)d_in[1];    // [1,1]
    const float* kern  = (const float*)d_in[2];    // [1,1]
    float* out = (float*)d_out;                    // T outputs + 1 new_state

    const size_t T = (size_t)in_sizes[0];
    const int nblocks = (int)(T / BLK_ELEMS);      // 256 for T=2^23

    uint32_t* counter = (uint32_t*)d_ws;
    uint64_t* agg = (uint64_t*)((char*)d_ws + 16);

    hipMemsetAsync(d_ws, 0, 16, stream);           // zero arrive-counter only
    phi_scan<<<nblocks, TPB, 0, stream>>>(x4, kern, state, out,
                                          agg, counter, nblocks);
}